// Round 1
// baseline (8395.967 us; speedup 1.0000x reference)
//
#include <hip/hip_runtime.h>
#include <cstdint>
#include <cstddef>

// Problem constants (match reference)
#define A_NUM_ANTS   16384
#define N_NODES      512
#define N_STEPS      511      // NUM_NODES - 1 scan steps
#define N_BATCH      4096

// ---------------------------------------------------------------------------
// Threefry-2x32 (20 rounds), exactly as in jax._src.prng.threefry2x32.
// Host/constexpr copy (for the subkey table).
// ---------------------------------------------------------------------------
constexpr uint32_t rotl32(uint32_t x, int r) { return (x << r) | (x >> (32 - r)); }

constexpr void tf2x32(uint32_t k0, uint32_t k1, uint32_t x0, uint32_t x1,
                      uint32_t& o0, uint32_t& o1) {
  const uint32_t k2 = k0 ^ k1 ^ 0x1BD11BDAu;
  x0 += k0; x1 += k1;
  x0 += x1; x1 = rotl32(x1, 13); x1 ^= x0;
  x0 += x1; x1 = rotl32(x1, 15); x1 ^= x0;
  x0 += x1; x1 = rotl32(x1, 26); x1 ^= x0;
  x0 += x1; x1 = rotl32(x1,  6); x1 ^= x0;
  x0 += k1; x1 += k2 + 1u;
  x0 += x1; x1 = rotl32(x1, 17); x1 ^= x0;
  x0 += x1; x1 = rotl32(x1, 29); x1 ^= x0;
  x0 += x1; x1 = rotl32(x1, 16); x1 ^= x0;
  x0 += x1; x1 = rotl32(x1, 24); x1 ^= x0;
  x0 += k2; x1 += k0 + 2u;
  x0 += x1; x1 = rotl32(x1, 13); x1 ^= x0;
  x0 += x1; x1 = rotl32(x1, 15); x1 ^= x0;
  x0 += x1; x1 = rotl32(x1, 26); x1 ^= x0;
  x0 += x1; x1 = rotl32(x1,  6); x1 ^= x0;
  x0 += k0; x1 += k1 + 3u;
  x0 += x1; x1 = rotl32(x1, 17); x1 ^= x0;
  x0 += x1; x1 = rotl32(x1, 29); x1 ^= x0;
  x0 += x1; x1 = rotl32(x1, 16); x1 ^= x0;
  x0 += x1; x1 = rotl32(x1, 24); x1 ^= x0;
  x0 += k1; x1 += k2 + 4u;
  x0 += x1; x1 = rotl32(x1, 13); x1 ^= x0;
  x0 += x1; x1 = rotl32(x1, 15); x1 ^= x0;
  x0 += x1; x1 = rotl32(x1, 26); x1 ^= x0;
  x0 += x1; x1 = rotl32(x1,  6); x1 ^= x0;
  x0 += k2; x1 += k0 + 5u;
  o0 = x0; o1 = x1;
}

// Sequential key-split chain from jax.random.key(42), foldlike split
// (jax_threefry_partitionable=True — CONFIRMED bit-exact R3..R7):
//   key_{t+1} = TF(key_t, (0,0));  sub_t = TF(key_t, (0,1))
struct Subkeys { uint32_t k0[N_STEPS]; uint32_t k1[N_STEPS]; };

constexpr Subkeys make_subkeys() {
  Subkeys s{};
  uint32_t c0 = 0u, c1 = 42u;          // key data = (hi, lo) of seed 42
  for (int t = 0; t < N_STEPS; ++t) {
    uint32_t n0 = 0, n1 = 0, s0 = 0, s1 = 0;
    tf2x32(c0, c1, 0u, 0u, n0, n1);
    tf2x32(c0, c1, 0u, 1u, s0, s1);
    s.k0[t] = s0; s.k1[t] = s1;
    c0 = n0; c1 = n1;
  }
  return s;
}

namespace { constexpr Subkeys H_SUBKEYS = make_subkeys(); }
__device__ __constant__ Subkeys SUBKEYS = H_SUBKEYS;

#define NEG_LN2   (-0.69314718056f)

// ---------------------------------------------------------------------------
// Device threefry: guaranteed single-instruction rotates (v_alignbit_b32) and
// the x1-init (ctr + k1, arithmetic identical mod 2^32) folded in by caller.
// Returns the partitionable fold o0 ^ o1 (FULL 32 bits; >>9 deferred).
// ---------------------------------------------------------------------------
__device__ __forceinline__ uint32_t drotl(uint32_t x, int r) {
  return __builtin_rotateleft32(x, (uint32_t)r);
}

__device__ __forceinline__ uint32_t tf_hash(uint32_t k0, uint32_t k1,
                                            uint32_t k2, uint32_t x1i) {
  uint32_t x0 = k0, x1 = x1i;     // == (0+k0, ctr+k1) of the reference tf
#define TFR(r) { x0 += x1; x1 = drotl(x1, r); x1 ^= x0; }
  TFR(13) TFR(15) TFR(26) TFR(6)
  x0 += k1; x1 += k2 + 1u;
  TFR(17) TFR(29) TFR(16) TFR(24)
  x0 += k2; x1 += k0 + 2u;
  TFR(13) TFR(15) TFR(26) TFR(6)
  x0 += k0; x1 += k1 + 3u;
  TFR(17) TFR(29) TFR(16) TFR(24)
  x0 += k1; x1 += k2 + 4u;
  TFR(13) TFR(15) TFR(26) TFR(6)
  x0 += k2; x1 += k0 + 5u;
#undef TFR
  return x0 ^ x1;
}

__device__ __forceinline__ uint32_t umax(uint32_t a, uint32_t b) {
  return a > b ? a : b;           // max(max(a,b),c) chains -> v_max3_u32
}

struct Frag { uint32_t m[8]; };   // per-lane RAW 32-bit draws (o0^o1), 8 cells

// ---------------------------------------------------------------------------
// Per-ant simulation: one wave per ant; lane l owns nodes l*8..l*8+7.
// Partitionable random_bits: bits(a,n) = w0^w1 of TF(sub_t, (0, a*512+n)).
// Exact score (R4..R7, absmax=0-verified): s = __log2f(f)*le with
// f = m*2^-23 exactly (m = bits>>9), le = -ln2*exp(-logit) (visited -> -ln2);
// argmin(s) == ref argmax(gumbel+logit), first-index ties.
//
// R9 changes (all bit-exact-equivalent to R8):
//  * filter compares RAW 32-bit draws against thr32 = mthr<<9.
//      x>>9 >= mthr  <=>  x >= mthr<<9   (low 9 bits of thr32 are zero), and
//      max(x)>>9 == max(x>>9)            (>>9 is monotone)
//    -> the 8 per-step v_lshrrev disappear from the hot path; slow path
//    (~0.2% of steps) reconstructs m = x>>9 locally.
//  * sentinel threshold replaced by an SGPR force_slow flag (same decisions).
//  * visited kept as 8 wave-uniform u64 masks in SGPRs (bit l of vq[q] ==
//    node l*8+q): the per-step update is pure SALU (s_cselect+s_or), the
//    per-lane bit is only read on the rare slow path.
//  * a/pos/slow-path bn/eb-range are readfirstlane'd so divergence analysis
//    keeps the whole bookkeeping chain scalar (SALU pipe is nearly idle).
//  * bpermute byte-addresses pinned in VGPRs (opaque asm) -> no per-use remat.
//  * local max shaped for v_max3_u32 (4 ops instead of 7).
//
// R8 pipeline kept: step t+1's hashes are outcome-independent -> computed in
// the same basic block as t's reduction (double-buffered Frags, 2x unroll).
// ---------------------------------------------------------------------------
template <bool WRITE_PATH>
__device__ __forceinline__ void simulate_ant(
    int a, int lane,
    const float* __restrict__ pher,
    const float* __restrict__ heur,
    int pos,
    float* __restrict__ plen_out,    // [A]   (!WRITE_PATH)
    float* __restrict__ path_out)    // [512] (WRITE_PATH)
{
  // a and pos are wave-uniform by construction; make that provable.
  a   = __builtin_amdgcn_readfirstlane(a);
  pos = __builtin_amdgcn_readfirstlane(pos);

  float lm[8];                     // UNVISITED coeff -ln2*exp(-base)
  unsigned long long vq[8];        // visited masks: bit l of vq[q] = node l*8+q
  float ebmin, ebmax;              // range of exp(-base), incl 1.0 (visited)
  {
    const float* hrow = heur + (size_t)pos * N_NODES;
    const float* prow = pher + (size_t)pos * N_NODES;
    ebmin = 1.0f; ebmax = 1.0f;    // include visited value exp(0)=1
#pragma unroll
    for (int q = 0; q < 8; ++q) {
      const int n = lane * 8 + q;
      const float hv = hrow[n];
      const float base = prow[n] * (hv * hv);   // p^1 * h^2
      const float eb = expf(-base);
      lm[q] = NEG_LN2 * eb;
      ebmin = fminf(ebmin, eb);
      ebmax = fmaxf(ebmax, eb);
      vq[q] = 0ull;
    }
    vq[pos & 7] = 1ull << (pos >> 3);           // start node visited
  }

  // Hoisted butterfly bpermute byte-addresses (lane^off)<<2, pinned so the
  // allocator keeps them live instead of re-materializing v_xor per use.
  int baddr[6];
#pragma unroll
  for (int r = 0; r < 6; ++r) {
    baddr[r] = ((lane ^ (1 << r)) << 2);
    asm volatile("" : "+v"(baddr[r]));
  }

  // Wave-wide eb range -> conservative integer-filter slope (one-time).
#pragma unroll
  for (int r = 0; r < 6; ++r) {
    ebmin = fminf(ebmin, __int_as_float(
        __builtin_amdgcn_ds_bpermute(baddr[r], __float_as_int(ebmin))));
    ebmax = fmaxf(ebmax, __int_as_float(
        __builtin_amdgcn_ds_bpermute(baddr[r], __float_as_int(ebmax))));
  }
  // wave-uniform after the butterfly; force scalar so the whole slope chain
  // and the fast/slow branch are SALU + s_cbranch.
  ebmin = __int_as_float(__builtin_amdgcn_readfirstlane(__float_as_int(ebmin)));
  ebmax = __int_as_float(__builtin_amdgcn_readfirstlane(__float_as_int(ebmax)));
  const float ratio = ebmax / ebmin;                       // >= 1
  const float delta = ratio * (1.0f + 3e-4f) - 1.0f + 1e-5f;
  const float d15   = delta * 1.5f;
  const bool  always_slow = !(d15 < 0.4f);                 // also catches NaN
  const uint32_t D32 = always_slow ? 0xFFFFFFFFu
                     : ((uint32_t)(d15 * 4294967296.0f) + 1u);

  int   cur  = pos;     // wave-uniform (SGPR)
  float plen = 0.0f;    // wave-uniform (redundantly computed by all lanes)
  if (WRITE_PATH && lane == 0) path_out[0] = (float)pos;

  const uint32_t ctr_base = (uint32_t)(a * N_NODES + lane * 8);

  // 8 hashes for one step -> raw 32-bit draws (no >>9 here)
  auto hash8 = [&](Frag& f, int t) __attribute__((always_inline)) {
    const uint32_t k0 = SUBKEYS.k0[t];
    const uint32_t k1 = SUBKEYS.k1[t];
    const uint32_t k2 = k0 ^ k1 ^ 0x1BD11BDAu;
#pragma unroll
    for (int q = 0; q < 8; ++q)
      f.m[q] = tf_hash(k0, k1, k2, ctr_base + (k1 + (uint32_t)q));
  };

  // one simulation step using `use`; optionally prefetch hashes for step
  // tpre into `pre` (independent work placed in the same BB for scheduling)
  auto step = [&](Frag& use, Frag& pre, int t, int tpre, bool do_pre)
      __attribute__((always_inline)) {
    // wave max of raw draws (monotone in m = x>>9); max3-shaped local tree
    const uint32_t t0 = umax(umax(use.m[0], use.m[1]), use.m[2]);
    const uint32_t t1 = umax(umax(use.m[3], use.m[4]), use.m[5]);
    const uint32_t t2 = umax(umax(use.m[6], use.m[7]), t0);
    uint32_t xmax = umax(t1, t2);
#pragma unroll
    for (int r = 0; r < 6; ++r) {
      const uint32_t o = (uint32_t)__builtin_amdgcn_ds_bpermute(baddr[r], (int)xmax);
      xmax = umax(xmax, o);
    }

    if (do_pre) hash8(pre, tpre);   // fills the bpermute-wait bubbles

    // integer threshold, SALU after readfirstlane (wave-uniform)
    const uint32_t xmax_s = (uint32_t)__builtin_amdgcn_readfirstlane((int)xmax);
    const uint32_t mmax_s = xmax_s >> 9;
    const uint32_t d   = 8388608u - mmax_s;
    const uint32_t sub = __umulhi(D32, d) + 2u;
    const uint32_t thr32 = (mmax_s - sub) << 9;   // low 9 bits zero
    const bool force_slow = always_slow || (mmax_s < 4194304u);

    // candidate ballots in the RAW domain (8 v_cmp; popcounts/sums on SALU)
    unsigned long long b[8];
    int tot = 0;
#pragma unroll
    for (int q = 0; q < 8; ++q) {
      b[q] = __ballot(use.m[q] >= thr32);
      tot += __popcll(b[q]);
    }

    int bn;
    if (!force_slow && tot == 1) {
      // unique filter-passer == winner; pure SALU index extraction
      bn = 0;
#pragma unroll
      for (int q = 0; q < 8; ++q)
        if (b[q]) bn = (int)__builtin_ctzll(b[q]) * 8 + q;
    } else {
      // exact path — bit-identical to R5/R7 (verified absmax=0)
      float s[8];
#pragma unroll
      for (int q = 0; q < 8; ++q) {
        const uint32_t m  = use.m[q] >> 9;       // reconstruct 23-bit mantissa
        const float f  = __uint_as_float(m | 0x3f800000u) - 1.0f;
        const float le = ((vq[q] >> lane) & 1ull) ? NEG_LN2 : lm[q];
        s[q] = __log2f(f) * le;                  // >= 0; f==0 -> +inf (loses)
      }
      float smin = s[0];
#pragma unroll
      for (int q = 1; q < 8; ++q) smin = fminf(smin, s[q]);
#pragma unroll
      for (int r = 0; r < 6; ++r)
        smin = fminf(smin, __int_as_float(
            __builtin_amdgcn_ds_bpermute(baddr[r], __float_as_int(smin))));
      int fq = 8;
#pragma unroll
      for (int q = 7; q >= 0; --q) if (s[q] == smin) fq = q;
      const unsigned long long mask = __ballot(fq < 8);
      const int winlane = __builtin_ctzll(mask);          // lowest match lane
      // lowest n overall; readfirstlane keeps bn provably uniform (SGPR)
      bn = __builtin_amdgcn_readfirstlane(__shfl(fq, winlane, 64)) + winlane * 8;
    }

    // mark winner visited — pure SALU (bn wave-uniform; vq in SGPR pairs)
    {
      const unsigned long long nb = 1ull << (bn >> 3);
      const int qq = bn & 7;
#pragma unroll
      for (int q = 0; q < 8; ++q) vq[q] |= (qq == q) ? nb : 0ull;
    }

    // wave-uniform bookkeeping (exact reference add order)
    plen += heur[(size_t)cur * N_NODES + bn];
    cur = bn;
    if (WRITE_PATH && lane == 0) path_out[t + 1] = (float)bn;
  };

  Frag A, B;
  hash8(A, 0);                                   // prologue
  for (int tt = 0; tt < (N_STEPS - 1) / 2; ++tt) {   // 255 pairs: t=0..509
    const int t0 = 2 * tt;
    step(A, B, t0,     t0 + 1, true);
    step(B, A, t0 + 1, t0 + 2, true);
  }
  step(A, B, N_STEPS - 1, 0, false);             // t=510, no prefetch

  if (!WRITE_PATH && lane == 0) plen_out[a] = plen;
}

// Pass 1: all ants, path lengths only.
__global__ __launch_bounds__(256, 6) void aco_sim_kernel(
    const float* __restrict__ pher, const float* __restrict__ heur,
    const int* __restrict__ pos0, float* __restrict__ plen_out, int num_ants)
{
  const int a = (int)((blockIdx.x * blockDim.x + threadIdx.x) >> 6);
  const int lane = threadIdx.x & 63;
  if (a >= num_ants) return;
  simulate_ant<false>(a, lane, pher, heur, pos0[a], plen_out, nullptr);
}

// Pass 2: first-minimum argmin (jnp.argmin semantics), clamped result.
__global__ void aco_argmin_kernel(const float* __restrict__ plen,
                                  int* __restrict__ best, int num_ants) {
  const int tid = threadIdx.x;
  float bv = 3.4e38f;
  int   bi = 0;
  bool  have = false;
  for (int i = tid; i < num_ants; i += 256) {
    const float v = plen[i];
    if (!have || v < bv) { bv = v; bi = i; have = true; }
  }
#pragma unroll
  for (int off = 32; off >= 1; off >>= 1) {
    const float vo = __shfl_xor(bv, off, 64);
    const int   io = __shfl_xor(bi, off, 64);
    if (vo < bv || (vo == bv && io < bi)) { bv = vo; bi = io; }
  }
  __shared__ float sv[4];
  __shared__ int   si[4];
  const int w = tid >> 6;
  if ((tid & 63) == 0) { sv[w] = bv; si[w] = bi; }
  __syncthreads();
  if (tid == 0) {
    for (int j = 1; j < 4; ++j)
      if (sv[j] < bv || (sv[j] == bv && si[j] < bi)) { bv = sv[j]; bi = si[j]; }
    bi = bi < 0 ? 0 : (bi >= num_ants ? num_ants - 1 : bi);  // hard clamp
    *best = bi;
  }
}

// Pass 3: one wave re-simulates ONLY the winning ant -> out[0:512] (row 0).
// Bit-identical draws/filter/scores to pass 1 (same inlined function).
__global__ void aco_resim_kernel(const float* __restrict__ pher,
                                 const float* __restrict__ heur,
                                 const int* __restrict__ pos0,
                                 const int* __restrict__ best,
                                 float* __restrict__ path_out, int num_ants) {
  const int lane = threadIdx.x & 63;
  int a = *best;
  a = a < 0 ? 0 : (a >= num_ants ? num_ants - 1 : a);        // hard clamp
  simulate_ant<true>(a, lane, pher, heur, pos0[a], nullptr, path_out);
}

// Pass 4: copy row 0 -> rows 1..n_rows-1. Row 0 is READ-ONLY here (no race).
__global__ void aco_bcast_kernel(float* __restrict__ out, int total4) {
  const int j = (int)(blockIdx.x * blockDim.x + threadIdx.x);  // over rows 1..
  if (j >= total4) return;
  const int row  = 1 + (j >> 7);          // 128 float4s per 512-float row
  const int col4 = j & 127;
  const float4 v = reinterpret_cast<const float4*>(out)[col4]; // row 0
  reinterpret_cast<float4*>(out)[row * 128 + col4] = v;
}

// ---------------------------------------------------------------------------
extern "C" void kernel_launch(void* const* d_in, const int* in_sizes, int n_in,
                              void* d_out, int out_size, void* d_ws, size_t ws_size,
                              hipStream_t stream) {
  // inputs: 0=x (unused), 1=pheromone_trails f32[512,512],
  //         2=heuristic_info f32[512,512], 3=ant_positions i32[16384]
  const float* pher = (const float*)d_in[1];
  const float* heur = (const float*)d_in[2];
  const int*   pos  = (const int*)d_in[3];
  float* out = (float*)d_out;
  const int num_ants = in_sizes[3];               // 16384

  // d_out doubles as scratch (d_ws untouched):
  //   A: out[0:16384] = plen   B: out[16384] = best (int bits)
  //   C: out[0:512] = winning path (row 0)   D: rows 1.. = copies of row 0
  float* plen = out;
  int*   best = (int*)(out + A_NUM_ANTS);

  const int sim_blocks = (num_ants * 64 + 255) / 256;
  aco_sim_kernel<<<dim3(sim_blocks), dim3(256), 0, stream>>>(
      pher, heur, pos, plen, num_ants);
  aco_argmin_kernel<<<dim3(1), dim3(256), 0, stream>>>(plen, best, num_ants);
  aco_resim_kernel<<<dim3(1), dim3(64), 0, stream>>>(
      pher, heur, pos, best, out, num_ants);
  const int total4 = (out_size - N_NODES) / 4;    // float4s in rows 1..
  aco_bcast_kernel<<<dim3((total4 + 255) / 256), dim3(256), 0, stream>>>(
      out, total4);
}

// Round 2
// 8008.850 us; speedup vs baseline: 1.0483x; 1.0483x over previous
//
#include <hip/hip_runtime.h>
#include <cstdint>
#include <cstddef>

// Problem constants (match reference)
#define A_NUM_ANTS   16384
#define N_NODES      512
#define N_STEPS      511      // NUM_NODES - 1 scan steps
#define N_BATCH      4096

// ---------------------------------------------------------------------------
// Threefry-2x32 (20 rounds), exactly as in jax._src.prng.threefry2x32.
// Host/constexpr copy (for the subkey table).
// ---------------------------------------------------------------------------
constexpr uint32_t rotl32(uint32_t x, int r) { return (x << r) | (x >> (32 - r)); }

constexpr void tf2x32(uint32_t k0, uint32_t k1, uint32_t x0, uint32_t x1,
                      uint32_t& o0, uint32_t& o1) {
  const uint32_t k2 = k0 ^ k1 ^ 0x1BD11BDAu;
  x0 += k0; x1 += k1;
  x0 += x1; x1 = rotl32(x1, 13); x1 ^= x0;
  x0 += x1; x1 = rotl32(x1, 15); x1 ^= x0;
  x0 += x1; x1 = rotl32(x1, 26); x1 ^= x0;
  x0 += x1; x1 = rotl32(x1,  6); x1 ^= x0;
  x0 += k1; x1 += k2 + 1u;
  x0 += x1; x1 = rotl32(x1, 17); x1 ^= x0;
  x0 += x1; x1 = rotl32(x1, 29); x1 ^= x0;
  x0 += x1; x1 = rotl32(x1, 16); x1 ^= x0;
  x0 += x1; x1 = rotl32(x1, 24); x1 ^= x0;
  x0 += k2; x1 += k0 + 2u;
  x0 += x1; x1 = rotl32(x1, 13); x1 ^= x0;
  x0 += x1; x1 = rotl32(x1, 15); x1 ^= x0;
  x0 += x1; x1 = rotl32(x1, 26); x1 ^= x0;
  x0 += x1; x1 = rotl32(x1,  6); x1 ^= x0;
  x0 += k0; x1 += k1 + 3u;
  x0 += x1; x1 = rotl32(x1, 17); x1 ^= x0;
  x0 += x1; x1 = rotl32(x1, 29); x1 ^= x0;
  x0 += x1; x1 = rotl32(x1, 16); x1 ^= x0;
  x0 += x1; x1 = rotl32(x1, 24); x1 ^= x0;
  x0 += k1; x1 += k2 + 4u;
  x0 += x1; x1 = rotl32(x1, 13); x1 ^= x0;
  x0 += x1; x1 = rotl32(x1, 15); x1 ^= x0;
  x0 += x1; x1 = rotl32(x1, 26); x1 ^= x0;
  x0 += x1; x1 = rotl32(x1,  6); x1 ^= x0;
  x0 += k2; x1 += k0 + 5u;
  o0 = x0; o1 = x1;
}

// Sequential key-split chain from jax.random.key(42), foldlike split
// (jax_threefry_partitionable=True — CONFIRMED bit-exact R3..R7):
//   key_{t+1} = TF(key_t, (0,0));  sub_t = TF(key_t, (0,1))
// k2 precomputed per step (one less SALU op in the hot loop).
struct Subkeys { uint32_t k0[N_STEPS]; uint32_t k1[N_STEPS]; uint32_t k2[N_STEPS]; };

constexpr Subkeys make_subkeys() {
  Subkeys s{};
  uint32_t c0 = 0u, c1 = 42u;          // key data = (hi, lo) of seed 42
  for (int t = 0; t < N_STEPS; ++t) {
    uint32_t n0 = 0, n1 = 0, s0 = 0, s1 = 0;
    tf2x32(c0, c1, 0u, 0u, n0, n1);
    tf2x32(c0, c1, 0u, 1u, s0, s1);
    s.k0[t] = s0; s.k1[t] = s1; s.k2[t] = s0 ^ s1 ^ 0x1BD11BDAu;
    c0 = n0; c1 = n1;
  }
  return s;
}

namespace { constexpr Subkeys H_SUBKEYS = make_subkeys(); }
__device__ __constant__ Subkeys SUBKEYS = H_SUBKEYS;

#define NEG_LN2   (-0.69314718056f)

// ---------------------------------------------------------------------------
// Device threefry: single-instruction rotates (v_alignbit_b32); the x1-init
// (ctr + k1, arithmetic identical mod 2^32) is folded in by the caller.
// Returns the partitionable fold o0 ^ o1 (FULL 32 bits; >>9 deferred).
// ---------------------------------------------------------------------------
__device__ __forceinline__ uint32_t drotl(uint32_t x, int r) {
  return __builtin_rotateleft32(x, (uint32_t)r);
}

__device__ __forceinline__ uint32_t tf_hash(uint32_t k0, uint32_t k1,
                                            uint32_t k2, uint32_t x1i) {
  uint32_t x0 = k0, x1 = x1i;     // == (0+k0, ctr+k1) of the reference tf
#define TFR(r) { x0 += x1; x1 = drotl(x1, r); x1 ^= x0; }
  TFR(13) TFR(15) TFR(26) TFR(6)
  x0 += k1; x1 += k2 + 1u;
  TFR(17) TFR(29) TFR(16) TFR(24)
  x0 += k2; x1 += k0 + 2u;
  TFR(13) TFR(15) TFR(26) TFR(6)
  x0 += k0; x1 += k1 + 3u;
  TFR(17) TFR(29) TFR(16) TFR(24)
  x0 += k1; x1 += k2 + 4u;
  TFR(13) TFR(15) TFR(26) TFR(6)
  x0 += k2; x1 += k0 + 5u;
#undef TFR
  return x0 ^ x1;
}

__device__ __forceinline__ uint32_t umax(uint32_t a, uint32_t b) {
  return a > b ? a : b;           // max(max(a,b),c) chains -> v_max3_u32
}

// Canonical GCN wave64 max-reduction on the VALU via DPP (no LDS pipe, no
// address VGPRs, no lgkmcnt waits). After the 6 fused v_max_u32_dpp steps,
// lane 63 holds the wave-wide max. old=0 => invalid source lanes contribute
// 0, which is identity for unsigned max (safe for either bound_ctrl sense).
__device__ __forceinline__ uint32_t wave_umax_dpp(uint32_t x) {
  x = umax(x, (uint32_t)__builtin_amdgcn_update_dpp(0, (int)x, 0x111, 0xf, 0xf, false)); // row_shr:1
  x = umax(x, (uint32_t)__builtin_amdgcn_update_dpp(0, (int)x, 0x112, 0xf, 0xf, false)); // row_shr:2
  x = umax(x, (uint32_t)__builtin_amdgcn_update_dpp(0, (int)x, 0x114, 0xf, 0xf, false)); // row_shr:4
  x = umax(x, (uint32_t)__builtin_amdgcn_update_dpp(0, (int)x, 0x118, 0xf, 0xf, false)); // row_shr:8
  x = umax(x, (uint32_t)__builtin_amdgcn_update_dpp(0, (int)x, 0x142, 0xf, 0xf, false)); // row_bcast:15
  x = umax(x, (uint32_t)__builtin_amdgcn_update_dpp(0, (int)x, 0x143, 0xf, 0xf, false)); // row_bcast:31
  return x;                        // lane 63 = wave max
}

struct Frag { uint32_t m[8]; };   // per-lane RAW 32-bit draws (o0^o1), 8 cells

// ---------------------------------------------------------------------------
// Per-ant simulation: one wave per ant; lane l owns nodes l*8..l*8+7.
// Partitionable random_bits: bits(a,n) = w0^w1 of TF(sub_t, (0, a*512+n)).
// Exact score (R4..R7, absmax=0-verified): s = __log2f(f)*le with
// f = m*2^-23 exactly (m = bits>>9), le = -ln2*exp(-logit) (visited -> -ln2);
// argmin(s) == ref argmax(gumbel+logit), first-index ties.
//
// R10 changes (bit-exact-equivalent; driven by R9's post-mortem that TOTAL
// issue slots/step — SALU included — is the cost currency):
//  * fast-path wave max via DPP reduction (wave_umax_dpp) + v_readlane(63):
//    removes 6 ds_bpermute issues, their waits, the 6-address VGPRs, and the
//    ~360-cycle serial butterfly latency chain per step.
//  * visited reverted to R8 per-lane u32 bitmask (3 VALU + 2 SALU per step
//    vs R9's ~18 SALU) — undoes R9's measured regression.
//  * raw-domain filter kept from R9: ballots compare 32-bit draws against
//    thr32 = mthr<<9 (x>>9 >= mthr <=> x >= mthr<<9; max monotone under >>9).
//  * k2 from the constant table; ctr_base+k1 hoisted once per hash8.
//  * slow-path / init reductions via __shfl_xor (ds_swizzle, no addr regs) —
//    they run ~0.2% of steps / once.
//
// R8 pipeline kept: step t+1's hashes are outcome-independent -> computed in
// the same basic block as t's reduction (double-buffered Frags, 2x unroll).
// ---------------------------------------------------------------------------
template <bool WRITE_PATH>
__device__ __forceinline__ void simulate_ant(
    int a, int lane,
    const float* __restrict__ pher,
    const float* __restrict__ heur,
    int pos,
    float* __restrict__ plen_out,    // [A]   (!WRITE_PATH)
    float* __restrict__ path_out)    // [512] (WRITE_PATH)
{
  // a and pos are wave-uniform by construction; make that provable.
  a   = __builtin_amdgcn_readfirstlane(a);
  pos = __builtin_amdgcn_readfirstlane(pos);

  float    lm[8];        // UNVISITED coeff -ln2*exp(-base); never modified
  uint32_t visited = 0;  // bit q: cell lane*8+q visited
  float    ebmin, ebmax; // range of exp(-base) across wave, incl 1.0 (visited)
  {
    const float* hrow = heur + (size_t)pos * N_NODES;
    const float* prow = pher + (size_t)pos * N_NODES;
    ebmin = 1.0f; ebmax = 1.0f;   // include visited value exp(0)=1
#pragma unroll
    for (int q = 0; q < 8; ++q) {
      const int n = lane * 8 + q;
      const float hv = hrow[n];
      const float base = prow[n] * (hv * hv);   // p^1 * h^2
      const float eb = expf(-base);
      lm[q] = NEG_LN2 * eb;
      ebmin = fminf(ebmin, eb);
      ebmax = fmaxf(ebmax, eb);
      if (n == pos) visited |= (1u << q);       // start node visited
    }
  }

  // Wave-wide eb range -> conservative integer-filter slope (one-time).
#pragma unroll
  for (int off = 1; off < 64; off <<= 1) {
    ebmin = fminf(ebmin, __shfl_xor(ebmin, off, 64));
    ebmax = fmaxf(ebmax, __shfl_xor(ebmax, off, 64));
  }
  // wave-uniform after the butterfly; force scalar so the slope chain and the
  // fast/slow branch are SALU + s_cbranch.
  ebmin = __int_as_float(__builtin_amdgcn_readfirstlane(__float_as_int(ebmin)));
  ebmax = __int_as_float(__builtin_amdgcn_readfirstlane(__float_as_int(ebmax)));
  const float ratio = ebmax / ebmin;                       // >= 1
  const float delta = ratio * (1.0f + 3e-4f) - 1.0f + 1e-5f;
  const float d15   = delta * 1.5f;
  const bool  always_slow = !(d15 < 0.4f);                 // also catches NaN
  const uint32_t D32 = always_slow ? 0xFFFFFFFFu
                     : ((uint32_t)(d15 * 4294967296.0f) + 1u);

  int   cur  = pos;     // wave-uniform
  float plen = 0.0f;    // wave-uniform (redundantly computed by all lanes)
  if (WRITE_PATH && lane == 0) path_out[0] = (float)pos;

  const uint32_t ctr_base = (uint32_t)(a * N_NODES + lane * 8);

  // 8 hashes for one step -> raw 32-bit draws (no >>9 here)
  auto hash8 = [&](Frag& f, int t) __attribute__((always_inline)) {
    const uint32_t k0 = SUBKEYS.k0[t];
    const uint32_t k1 = SUBKEYS.k1[t];
    const uint32_t k2 = SUBKEYS.k2[t];
    const uint32_t xb = ctr_base + k1;          // hoisted: one VALU add
#pragma unroll
    for (int q = 0; q < 8; ++q)
      f.m[q] = tf_hash(k0, k1, k2, xb + (uint32_t)q);
  };

  // one simulation step using `use`; optionally prefetch hashes for step
  // tpre into `pre` (independent work placed in the same BB for scheduling)
  auto step = [&](Frag& use, Frag& pre, int t, int tpre, bool do_pre)
      __attribute__((always_inline)) {
    // wave max of raw draws (monotone in m = x>>9); max3-shaped local tree
    const uint32_t t0 = umax(umax(use.m[0], use.m[1]), use.m[2]);
    const uint32_t t1 = umax(umax(use.m[3], use.m[4]), use.m[5]);
    const uint32_t t2 = umax(umax(use.m[6], use.m[7]), t0);
    const uint32_t xmax = wave_umax_dpp(umax(t1, t2));     // lane 63 valid

    if (do_pre) hash8(pre, tpre);   // independent work for the scheduler

    // integer threshold, SALU after readlane (wave-uniform)
    const uint32_t xmax_s = (uint32_t)__builtin_amdgcn_readlane((int)xmax, 63);
    const uint32_t mmax_s = xmax_s >> 9;
    const uint32_t d   = 8388608u - mmax_s;
    const uint32_t sub = __umulhi(D32, d) + 2u;
    const uint32_t thr32 = (mmax_s - sub) << 9;   // low 9 bits zero
    const bool force_slow = always_slow || (mmax_s < 4194304u);

    // candidate ballots in the RAW domain (8 v_cmp; popcounts/sums on SALU)
    unsigned long long b[8];
    int tot = 0;
#pragma unroll
    for (int q = 0; q < 8; ++q) {
      b[q] = __ballot(use.m[q] >= thr32);
      tot += __popcll(b[q]);
    }

    int bn;
    if (!force_slow && tot == 1) {
      // unique filter-passer == winner; pure SALU index extraction
      bn = 0;
#pragma unroll
      for (int q = 0; q < 8; ++q)
        if (b[q]) bn = (int)__builtin_ctzll(b[q]) * 8 + q;
    } else {
      // exact path — bit-identical to R5/R7 (verified absmax=0)
      float s[8];
#pragma unroll
      for (int q = 0; q < 8; ++q) {
        const uint32_t m  = use.m[q] >> 9;       // reconstruct 23-bit mantissa
        const float f  = __uint_as_float(m | 0x3f800000u) - 1.0f;
        const float le = ((visited >> q) & 1u) ? NEG_LN2 : lm[q];
        s[q] = __log2f(f) * le;                  // >= 0; f==0 -> +inf (loses)
      }
      float smin = s[0];
#pragma unroll
      for (int q = 1; q < 8; ++q) smin = fminf(smin, s[q]);
#pragma unroll
      for (int off = 1; off < 64; off <<= 1)
        smin = fminf(smin, __shfl_xor(smin, off, 64));
      int fq = 8;
#pragma unroll
      for (int q = 7; q >= 0; --q) if (s[q] == smin) fq = q;
      const unsigned long long mask = __ballot(fq < 8);
      const int winlane = __builtin_ctzll(mask);          // lowest match lane
      // lowest n overall; readfirstlane keeps bn provably uniform (SGPR)
      bn = __builtin_amdgcn_readfirstlane(__shfl(fq, winlane, 64)) + winlane * 8;
    }

    // mark winner visited (bn wave-uniform; 3 VALU + 2 SALU)
    if ((bn >> 3) == lane) visited |= (1u << (bn & 7));

    // wave-uniform bookkeeping (exact reference add order)
    plen += heur[(size_t)cur * N_NODES + bn];
    cur = bn;
    if (WRITE_PATH && lane == 0) path_out[t + 1] = (float)bn;
  };

  Frag A, B;
  hash8(A, 0);                                   // prologue
  for (int tt = 0; tt < (N_STEPS - 1) / 2; ++tt) {   // 255 pairs: t=0..509
    const int t0 = 2 * tt;
    step(A, B, t0,     t0 + 1, true);
    step(B, A, t0 + 1, t0 + 2, true);
  }
  step(A, B, N_STEPS - 1, 0, false);             // t=510, no prefetch

  if (!WRITE_PATH && lane == 0) plen_out[a] = plen;
}

// Pass 1: all ants, path lengths only.
__global__ __launch_bounds__(256, 6) void aco_sim_kernel(
    const float* __restrict__ pher, const float* __restrict__ heur,
    const int* __restrict__ pos0, float* __restrict__ plen_out, int num_ants)
{
  const int a = (int)((blockIdx.x * blockDim.x + threadIdx.x) >> 6);
  const int lane = threadIdx.x & 63;
  if (a >= num_ants) return;
  simulate_ant<false>(a, lane, pher, heur, pos0[a], plen_out, nullptr);
}

// Pass 2: first-minimum argmin (jnp.argmin semantics), clamped result.
__global__ void aco_argmin_kernel(const float* __restrict__ plen,
                                  int* __restrict__ best, int num_ants) {
  const int tid = threadIdx.x;
  float bv = 3.4e38f;
  int   bi = 0;
  bool  have = false;
  for (int i = tid; i < num_ants; i += 256) {
    const float v = plen[i];
    if (!have || v < bv) { bv = v; bi = i; have = true; }
  }
#pragma unroll
  for (int off = 32; off >= 1; off >>= 1) {
    const float vo = __shfl_xor(bv, off, 64);
    const int   io = __shfl_xor(bi, off, 64);
    if (vo < bv || (vo == bv && io < bi)) { bv = vo; bi = io; }
  }
  __shared__ float sv[4];
  __shared__ int   si[4];
  const int w = tid >> 6;
  if ((tid & 63) == 0) { sv[w] = bv; si[w] = bi; }
  __syncthreads();
  if (tid == 0) {
    for (int j = 1; j < 4; ++j)
      if (sv[j] < bv || (sv[j] == bv && si[j] < bi)) { bv = sv[j]; bi = si[j]; }
    bi = bi < 0 ? 0 : (bi >= num_ants ? num_ants - 1 : bi);  // hard clamp
    *best = bi;
  }
}

// Pass 3: one wave re-simulates ONLY the winning ant -> out[0:512] (row 0).
// Bit-identical draws/filter/scores to pass 1 (same inlined function).
__global__ void aco_resim_kernel(const float* __restrict__ pher,
                                 const float* __restrict__ heur,
                                 const int* __restrict__ pos0,
                                 const int* __restrict__ best,
                                 float* __restrict__ path_out, int num_ants) {
  const int lane = threadIdx.x & 63;
  int a = *best;
  a = a < 0 ? 0 : (a >= num_ants ? num_ants - 1 : a);        // hard clamp
  simulate_ant<true>(a, lane, pher, heur, pos0[a], nullptr, path_out);
}

// Pass 4: copy row 0 -> rows 1..n_rows-1. Row 0 is READ-ONLY here (no race).
__global__ void aco_bcast_kernel(float* __restrict__ out, int total4) {
  const int j = (int)(blockIdx.x * blockDim.x + threadIdx.x);  // over rows 1..
  if (j >= total4) return;
  const int row  = 1 + (j >> 7);          // 128 float4s per 512-float row
  const int col4 = j & 127;
  const float4 v = reinterpret_cast<const float4*>(out)[col4]; // row 0
  reinterpret_cast<float4*>(out)[row * 128 + col4] = v;
}

// ---------------------------------------------------------------------------
extern "C" void kernel_launch(void* const* d_in, const int* in_sizes, int n_in,
                              void* d_out, int out_size, void* d_ws, size_t ws_size,
                              hipStream_t stream) {
  // inputs: 0=x (unused), 1=pheromone_trails f32[512,512],
  //         2=heuristic_info f32[512,512], 3=ant_positions i32[16384]
  const float* pher = (const float*)d_in[1];
  const float* heur = (const float*)d_in[2];
  const int*   pos  = (const int*)d_in[3];
  float* out = (float*)d_out;
  const int num_ants = in_sizes[3];               // 16384

  // d_out doubles as scratch (d_ws untouched):
  //   A: out[0:16384] = plen   B: out[16384] = best (int bits)
  //   C: out[0:512] = winning path (row 0)   D: rows 1.. = copies of row 0
  float* plen = out;
  int*   best = (int*)(out + A_NUM_ANTS);

  const int sim_blocks = (num_ants * 64 + 255) / 256;
  aco_sim_kernel<<<dim3(sim_blocks), dim3(256), 0, stream>>>(
      pher, heur, pos, plen, num_ants);
  aco_argmin_kernel<<<dim3(1), dim3(256), 0, stream>>>(plen, best, num_ants);
  aco_resim_kernel<<<dim3(1), dim3(64), 0, stream>>>(
      pher, heur, pos, best, out, num_ants);
  const int total4 = (out_size - N_NODES) / 4;    // float4s in rows 1..
  aco_bcast_kernel<<<dim3((total4 + 255) / 256), dim3(256), 0, stream>>>(
      out, total4);
}